// Round 24
// baseline (190.974 us; speedup 1.0000x reference)
//
#include <hip/hip_runtime.h>
#include <hip/hip_bf16.h>
#include <stdint.h>

// out[m][n] = (sum_k x[m][k] * W[n][k]) * scale[n]
// M=8192 (B*S), N=4096 (D_OUT), K=4096 (D_IN)
// x fp32, W int32 (harness materializes integer inputs as int32), scale fp32.
// INT8 path: W exact int8; x per-row symmetric int8 (sx=amax/127).
// GEMM via mfma_i32_32x32x32_i8 (4404 TOPS ubench, +11.7% vs 16x16x64, half
// the instructions). Schedule = r22's verified 8-phase skeleton. r23 bugfix:
// fragment rows restored to the HALF-PAIRING invariant (each phase's staging
// only overwrites the half freed by that phase's reads):
//   A m-offsets: A03 = {wr*32, 64+wr*32} (h0), A47 = +128 (h1)
//   B n-offsets: B01 = {wc*32} (h0),          B23 = +128 (h1)
// (r23's contiguous 64-row blocks put B23 in h0 for wc<2 -> ph1's stage
// clobbered it 2 barriers before the ph2 read.)
// Layouts (HW-verified): in row/col = lane&31, k = (lane>>5)*16+b (A,B same
// per-lane k-map -> permutation-safe); C/D col = lane&31,
// row = (e&3)+8*(e>>2)+4*(lane>>5). Read swizzle: phys chunk =
// (ks*2+lk5) ^ (l31&7); source pre-swizzled involution (rows ≡ l31 mod 8).
// vmcnt(6) at ph4/ph8 (never 0 mid-loop). T1 XCD swizzle, T5 setprio.

#define M_TOT 8192
#define N_TOT 4096
#define K_TOT 4096
#define BM 256
#define BN 256
#define BK 128            // bytes (i8) per row per k-tile
#define NT (K_TOT / BK)   // 32 k-tiles

typedef int intx4 __attribute__((ext_vector_type(4)));
typedef int intx16 __attribute__((ext_vector_type(16)));

__device__ __forceinline__ int pack4(int4 r) {
  return (r.x & 255) | ((r.y & 255) << 8) | ((r.z & 255) << 16) | (r.w << 24);
}

// ---- fused pre-pass: blocks [0,8192) quantize x rows; [8192,12288) pack W ----
__global__ void prep_kernel(const float* __restrict__ x,
                            const int* __restrict__ w,
                            int* __restrict__ q,        // packed x i8, 4/int
                            float* __restrict__ xs,     // [M] dequant scale
                            int4* __restrict__ wout) {  // W i8 row-major
  const int tid = threadIdx.x;
  if (blockIdx.x < M_TOT) {
    const int row = blockIdx.x;
    const float4* xr = (const float4*)(x + (size_t)row * K_TOT);
    float4 v[4];
#pragma unroll
    for (int j = 0; j < 4; ++j) v[j] = xr[tid + 256 * j];
    float am = 0.f;
#pragma unroll
    for (int j = 0; j < 4; ++j) {
      am = fmaxf(am, fmaxf(fmaxf(fabsf(v[j].x), fabsf(v[j].y)),
                           fmaxf(fabsf(v[j].z), fabsf(v[j].w))));
    }
#pragma unroll
    for (int off = 32; off >= 1; off >>= 1)
      am = fmaxf(am, __shfl_xor(am, off));
    __shared__ float wmax[4];
    if ((tid & 63) == 0) wmax[tid >> 6] = am;
    __syncthreads();
    am = fmaxf(fmaxf(wmax[0], wmax[1]), fmaxf(wmax[2], wmax[3]));
    const float inv = 127.0f / fmaxf(am, 1e-30f);
    int* qo = q + (size_t)row * (K_TOT / 4);
#pragma unroll
    for (int j = 0; j < 4; ++j) {
      int b0 = __float2int_rn(v[j].x * inv);
      int b1 = __float2int_rn(v[j].y * inv);
      int b2 = __float2int_rn(v[j].z * inv);
      int b3 = __float2int_rn(v[j].w * inv);
      qo[tid + 256 * j] =
          (b0 & 255) | ((b1 & 255) << 8) | ((b2 & 255) << 16) | (b3 << 24);
    }
    if (tid == 0) xs[row] = am * (1.0f / 127.0f);
  } else {
    const int i = (blockIdx.x - M_TOT) * 256 + tid;
    const int4* in4 = (const int4*)w;
    int4 r0 = in4[4 * i], r1 = in4[4 * i + 1];
    int4 r2 = in4[4 * i + 2], r3 = in4[4 * i + 3];
    int4 o;
    o.x = pack4(r0); o.y = pack4(r1); o.z = pack4(r2); o.w = pack4(r3);
    wout[i] = o;
  }
}

// ---- async global->LDS (16B per lane, wave-uniform dest + lane*16) ----
__device__ __forceinline__ void gload_lds16(const void* g, const void* l) {
  const __attribute__((address_space(1))) void* gp =
      reinterpret_cast<const __attribute__((address_space(1))) void*>(
          reinterpret_cast<uintptr_t>(g));
  __attribute__((address_space(3))) void* lp =
      reinterpret_cast<__attribute__((address_space(3))) void*>(
          (uint32_t)reinterpret_cast<uintptr_t>(l));
  __builtin_amdgcn_global_load_lds(gp, lp, 16, 0, 0);
}

#define BAR() __builtin_amdgcn_s_barrier()
#define VMCNT(N) asm volatile("s_waitcnt vmcnt(" #N ")" ::: "memory")

// ---- main GEMM: i8 32x32x32, 256x256 tile, BK=128B, 8 waves, 8-phase ----
__global__ __launch_bounds__(512, 2)
void wq_gemm_kernel(const char* __restrict__ A,     // [M][K] i8 (quantized x)
                    const char* __restrict__ B,     // [N][K] i8 (W rows)
                    const float* __restrict__ XS,   // [M] x dequant scale
                    const float* __restrict__ scale,// [N]
                    float* __restrict__ C) {        // [M][N]
  __shared__ __align__(16) char As[2][BM * BK];  // 2 x 32 KiB
  __shared__ __align__(16) char Bs[2][BN * BK];  // 2 x 32 KiB

  // XCD-aware block swizzle (nwg=512, divisible by 8)
  const int nb = gridDim.x;
  const int swz = (blockIdx.x & 7) * (nb >> 3) + (blockIdx.x >> 3);
  const int bm = swz >> 4;        // M/BM = 32
  const int bn = swz & 15;        // N/BN = 16

  const int tid = threadIdx.x;
  const int wave = tid >> 6, lane = tid & 63;
  const int wr = wave >> 2, wc = wave & 3;   // 2 x 4 wave grid
  const int l31 = lane & 31, lk5 = lane >> 5;
  const int l7q = l31 & 7;
  const int arow0 = wr * 32 + l31;    // + mp*64 (h0); +128 for A47 (h1)
  const int brow0 = wc * 32 + l31;    // h0; +128 for B23 (h1)

  intx16 acc[4][2] = {};   // [m-pos][n-pos], 128 AGPR
  intx4 af[2][4];          // current A half: 2 m-pos x 4 k-steps
  intx4 bf[2][4];          // [n-slot][k-step]

  // Staging identical to r22: one gload = 512 threads x 16B = 64 rows x
  // 128B; 8 per tile. LDS dest linear; source chunk pre-swizzled
  // (involution): phys chunk (tid&7) of row (tid>>3) <- logical
  // (tid&7) ^ ((tid>>3)&7).
  const int srow = tid >> 3;                       // 0..63
  const int sc16 = (tid & 7) ^ ((tid >> 3) & 7);
  const char* gA = A + (size_t)(bm * BM + srow) * K_TOT + sc16 * 16;
  const char* gB = B + (size_t)(bn * BN + srow) * K_TOT + sc16 * 16;

#define STAGE_A(P, J, KT)                                                 \
  gload_lds16(gA + (size_t)(J) * 64 * K_TOT + (size_t)(KT) * BK,          \
              As[P] + (J) * 8192 + wave * 1024)
#define STAGE_B(P, J, KT)                                                 \
  gload_lds16(gB + (size_t)(J) * 64 * K_TOT + (size_t)(KT) * BK,          \
              Bs[P] + (J) * 8192 + wave * 1024)

  // Swizzled fragment read: lane needs bytes [ks*32 + lk5*16, +16) of its
  // row; phys chunk = (ks*2 + lk5) ^ (row&7), row&7 == l7q for all frags.
#define DS16Q(BASE, ROW, KS)                                              \
  *(const intx4*)((BASE) + (ROW) * BK + ((((KS) * 2 + lk5) ^ l7q) << 4))

#define LD_A03(P)                                                         \
  _Pragma("unroll") for (int mp = 0; mp < 2; ++mp)                        \
  _Pragma("unroll") for (int ks = 0; ks < 4; ++ks)                        \
      af[mp][ks] = DS16Q(As[P], arow0 + mp * 64, ks);
#define LD_A47(P)                                                         \
  _Pragma("unroll") for (int mp = 0; mp < 2; ++mp)                        \
  _Pragma("unroll") for (int ks = 0; ks < 4; ++ks)                        \
      af[mp][ks] = DS16Q(As[P], arow0 + mp * 64 + 128, ks);
#define LD_B01(P)                                                         \
  _Pragma("unroll") for (int ks = 0; ks < 4; ++ks)                        \
      bf[0][ks] = DS16Q(Bs[P], brow0, ks);
#define LD_B23(P)                                                         \
  _Pragma("unroll") for (int ks = 0; ks < 4; ++ks)                        \
      bf[1][ks] = DS16Q(Bs[P], brow0 + 128, ks);

  // Quadrant: 2 m-pos x 1 n-slot x 4 k-steps = 8 MFMA (32x32x32 each);
  // k-steps ACCUMULATE into the same acc (K-loop recipe).
#define MFMA_Q(MH, NS)                                                    \
  __builtin_amdgcn_s_setprio(1);                                          \
  _Pragma("unroll") for (int mp2 = 0; mp2 < 2; ++mp2)                     \
  _Pragma("unroll") for (int ks2 = 0; ks2 < 4; ++ks2)                     \
      acc[(MH) * 2 + mp2][NS] = __builtin_amdgcn_mfma_i32_32x32x32_i8(    \
          af[mp2][ks2], bf[NS][ks2], acc[(MH) * 2 + mp2][NS], 0, 0, 0);   \
  __builtin_amdgcn_s_setprio(0)

  // ---- prologue: stage t0 (8 gloads), t1 (8); certify t0; bf[0](t0) ----
  STAGE_B(0, 0, 0); STAGE_B(0, 1, 0); STAGE_A(0, 0, 0); STAGE_A(0, 1, 0);
  STAGE_B(0, 2, 0); STAGE_B(0, 3, 0); STAGE_A(0, 2, 0); STAGE_A(0, 3, 0);
  STAGE_B(1, 0, 1); STAGE_B(1, 1, 1); STAGE_A(1, 0, 1); STAGE_A(1, 1, 1);
  STAGE_B(1, 2, 1); STAGE_B(1, 3, 1); STAGE_A(1, 2, 1); STAGE_A(1, 3, 1);
  VMCNT(8);
  BAR();
  LD_B01(0);

  // ---- main loop: computes (t: buf0, t+1: buf1), stages (t+2, t+3).
  // Per phase: {ds_reads; stage the half those reads just freed; [vmcnt(6)
  // at ph4/ph8 BEFORE next-tile B read]; BAR; 8 MFMA; BAR}.
  for (int t = 0; t + 3 < NT; t += 2) {
    LD_A03(0);
    STAGE_B(0, 0, t + 2); STAGE_B(0, 1, t + 2);
    BAR(); MFMA_Q(0, 0); BAR();
    LD_B23(0);
    STAGE_A(0, 0, t + 2); STAGE_A(0, 1, t + 2);
    BAR(); MFMA_Q(0, 1); BAR();
    LD_A47(0);
    STAGE_B(0, 2, t + 2); STAGE_B(0, 3, t + 2);
    BAR(); MFMA_Q(1, 0); BAR();
    VMCNT(6);
    LD_B01(1);
    STAGE_A(0, 2, t + 2); STAGE_A(0, 3, t + 2);
    BAR(); MFMA_Q(1, 1); BAR();
    LD_A03(1);
    STAGE_B(1, 0, t + 3); STAGE_B(1, 1, t + 3);
    BAR(); MFMA_Q(0, 0); BAR();
    LD_B23(1);
    STAGE_A(1, 0, t + 3); STAGE_A(1, 1, t + 3);
    BAR(); MFMA_Q(0, 1); BAR();
    LD_A47(1);
    STAGE_B(1, 2, t + 3); STAGE_B(1, 3, t + 3);
    BAR(); MFMA_Q(1, 0); BAR();
    VMCNT(6);
    LD_B01(0);
    STAGE_A(1, 2, t + 3); STAGE_A(1, 3, t + 3);
    BAR(); MFMA_Q(1, 1); BAR();
  }

  // ---- tail: tiles NT-2 (buf0), NT-1 (buf1), no staging ----
  LD_A03(0); BAR(); MFMA_Q(0, 0); BAR();
  LD_B23(0); BAR(); MFMA_Q(0, 1); BAR();
  LD_A47(0); BAR(); MFMA_Q(1, 0); BAR();
  VMCNT(0);
  LD_B01(1); BAR(); MFMA_Q(1, 1); BAR();
  LD_A03(1); BAR(); MFMA_Q(0, 0); BAR();
  LD_B23(1); BAR(); MFMA_Q(0, 1); BAR();
  LD_A47(1); BAR(); MFMA_Q(1, 0); BAR();
  MFMA_Q(1, 1);

  // ---- epilogue: 32x32 D mapping col = lane&31,
  // row = (e&3) + 8*(e>>2) + 4*(lane>>5); m-offset(mi) = (mi>>1)*128 +
  // (mi&1)*64 + wr*32; n-offset(ni) = ni*128 + wc*32. Dequant fused. ----
  const size_t crow0 = (size_t)bm * BM + wr * 32 + lk5 * 4;
  const int ccol0 = bn * BN + wc * 32 + l31;
  float sc2[2];
#pragma unroll
  for (int ni = 0; ni < 2; ++ni) sc2[ni] = scale[ccol0 + ni * 128];
#pragma unroll
  for (int mi = 0; mi < 4; ++mi) {
#pragma unroll
    for (int e = 0; e < 16; ++e) {
      const size_t r = crow0 + (mi >> 1) * 128 + (mi & 1) * 64 +
                       (e & 3) + 8 * (e >> 2);
      const float xr = XS[r];
#pragma unroll
      for (int ni = 0; ni < 2; ++ni)
        C[r * N_TOT + ccol0 + ni * 128] = (float)acc[mi][ni][e] * xr * sc2[ni];
    }
  }
}

// ---- fallback if workspace too small (insurance; slow but correct) ----
__global__ void naive_kernel(const float* __restrict__ x,
                             const int* __restrict__ w,
                             const float* __restrict__ s,
                             float* __restrict__ out) {
  int m = blockIdx.y;
  int n = blockIdx.x * 256 + threadIdx.x;
  const float* xr = x + (size_t)m * K_TOT;
  const int* wr = w + (size_t)n * K_TOT;
  float acc = 0.f;
  for (int k = 0; k < K_TOT; ++k) acc += xr[k] * (float)wr[k];
  out[(size_t)m * N_TOT + n] = acc * s[n];
}

extern "C" void kernel_launch(void* const* d_in, const int* in_sizes, int n_in,
                              void* d_out, int out_size, void* d_ws, size_t ws_size,
                              hipStream_t stream) {
  const float* x = (const float*)d_in[0];
  const int* w = (const int*)d_in[1];
  const float* scale = (const float*)d_in[2];
  float* out = (float*)d_out;

  const size_t x_elems = (size_t)M_TOT * K_TOT;   // i8 bytes
  const size_t w_elems = (size_t)N_TOT * K_TOT;   // i8 bytes
  const size_t need = x_elems + w_elems + M_TOT * sizeof(float);

  if (ws_size < need) {
    dim3 g(N_TOT / 256, M_TOT);
    naive_kernel<<<g, 256, 0, stream>>>(x, w, scale, out);
    return;
  }

  char* qx = (char*)d_ws;
  char* qw = qx + x_elems;
  float* xs = (float*)(qw + w_elems);

  const int prep_grid = M_TOT + (int)(w_elems / 16 / 256);  // 8192 + 4096
  prep_kernel<<<prep_grid, 256, 0, stream>>>(
      x, w, (int*)qx, xs, (int4*)qw);

  wq_gemm_kernel<<<(M_TOT / BM) * (N_TOT / BN), 512, 0, stream>>>(
      qx, qw, xs, scale, out);
}

// Round 25
// 170.740 us; speedup vs baseline: 1.1185x; 1.1185x over previous
//
#include <hip/hip_runtime.h>
#include <hip/hip_bf16.h>
#include <stdint.h>

// out[m][n] = (sum_k x[m][k] * W[n][k]) * scale[n]
// M=8192 (B*S), N=4096 (D_OUT), K=4096 (D_IN)
// x fp32, W int32 (harness materializes integer inputs as int32), scale fp32.
// INT8 path: W exact int8; x per-row symmetric int8 (sx=amax/127).
// GEMM via mfma_i32_16x16x64_i8. Dequant: out = acc * sx[row] * scale[col].
// FINAL (r22, session best: 171.3 us total, GEMM 136 us, 0 conflicts):
// 8-phase schedule, 256x256 tile, BK=128B (NT=32), 8 waves 2x4, double-
// buffered A+B LDS (128 KiB), per tile 4 phases {reads(8/4/8/4); stage 1
// half-tile; BAR; 16 MFMA; BAR}, snaked quadrants (B-slot read one phase
// early), vmcnt(6) at ph4/ph8 BEFORE the next-tile B read (3 staged halves
// in flight; never 0 mid-loop). Swizzle: phys 16B-chunk = (lk+4*kk)^(row&7),
// source pre-swizzled involution (measured 0 conflicts). T1 XCD swizzle,
// T5 setprio, fused prep (quant_x + pack_w in one launch).
// r24's 32x32x32 variant regressed (bank conflicts structural to 32-row
// fragment reads) -- reverted per pre-commitment.

#define M_TOT 8192
#define N_TOT 4096
#define K_TOT 4096
#define BM 256
#define BN 256
#define BK 128            // bytes (i8) per row per k-tile
#define NT (K_TOT / BK)   // 32 k-tiles

typedef int intx4 __attribute__((ext_vector_type(4)));

__device__ __forceinline__ int pack4(int4 r) {
  return (r.x & 255) | ((r.y & 255) << 8) | ((r.z & 255) << 16) | (r.w << 24);
}

// ---- fused pre-pass: blocks [0,8192) quantize x rows; [8192,12288) pack W ----
__global__ void prep_kernel(const float* __restrict__ x,
                            const int* __restrict__ w,
                            int* __restrict__ q,        // packed x i8, 4/int
                            float* __restrict__ xs,     // [M] dequant scale
                            int4* __restrict__ wout) {  // W i8 row-major
  const int tid = threadIdx.x;
  if (blockIdx.x < M_TOT) {
    const int row = blockIdx.x;
    const float4* xr = (const float4*)(x + (size_t)row * K_TOT);
    float4 v[4];
#pragma unroll
    for (int j = 0; j < 4; ++j) v[j] = xr[tid + 256 * j];
    float am = 0.f;
#pragma unroll
    for (int j = 0; j < 4; ++j) {
      am = fmaxf(am, fmaxf(fmaxf(fabsf(v[j].x), fabsf(v[j].y)),
                           fmaxf(fabsf(v[j].z), fabsf(v[j].w))));
    }
#pragma unroll
    for (int off = 32; off >= 1; off >>= 1)
      am = fmaxf(am, __shfl_xor(am, off));
    __shared__ float wmax[4];
    if ((tid & 63) == 0) wmax[tid >> 6] = am;
    __syncthreads();
    am = fmaxf(fmaxf(wmax[0], wmax[1]), fmaxf(wmax[2], wmax[3]));
    const float inv = 127.0f / fmaxf(am, 1e-30f);
    int* qo = q + (size_t)row * (K_TOT / 4);
#pragma unroll
    for (int j = 0; j < 4; ++j) {
      int b0 = __float2int_rn(v[j].x * inv);
      int b1 = __float2int_rn(v[j].y * inv);
      int b2 = __float2int_rn(v[j].z * inv);
      int b3 = __float2int_rn(v[j].w * inv);
      qo[tid + 256 * j] =
          (b0 & 255) | ((b1 & 255) << 8) | ((b2 & 255) << 16) | (b3 << 24);
    }
    if (tid == 0) xs[row] = am * (1.0f / 127.0f);
  } else {
    const int i = (blockIdx.x - M_TOT) * 256 + tid;
    const int4* in4 = (const int4*)w;
    int4 r0 = in4[4 * i], r1 = in4[4 * i + 1];
    int4 r2 = in4[4 * i + 2], r3 = in4[4 * i + 3];
    int4 o;
    o.x = pack4(r0); o.y = pack4(r1); o.z = pack4(r2); o.w = pack4(r3);
    wout[i] = o;
  }
}

// ---- async global->LDS (16B per lane, wave-uniform dest + lane*16) ----
__device__ __forceinline__ void gload_lds16(const void* g, const void* l) {
  const __attribute__((address_space(1))) void* gp =
      reinterpret_cast<const __attribute__((address_space(1))) void*>(
          reinterpret_cast<uintptr_t>(g));
  __attribute__((address_space(3))) void* lp =
      reinterpret_cast<__attribute__((address_space(3))) void*>(
          (uint32_t)reinterpret_cast<uintptr_t>(l));
  __builtin_amdgcn_global_load_lds(gp, lp, 16, 0, 0);
}

#define BAR() __builtin_amdgcn_s_barrier()
#define VMCNT(N) asm volatile("s_waitcnt vmcnt(" #N ")" ::: "memory")

// ---- main GEMM: i8, 256x256 tile, BK=128B, 8 waves (2x4), 8-phase ----
__global__ __launch_bounds__(512, 2)
void wq_gemm_kernel(const char* __restrict__ A,     // [M][K] i8 (quantized x)
                    const char* __restrict__ B,     // [N][K] i8 (W rows)
                    const float* __restrict__ XS,   // [M] x dequant scale
                    const float* __restrict__ scale,// [N]
                    float* __restrict__ C) {        // [M][N]
  __shared__ __align__(16) char As[2][BM * BK];  // 2 x 32 KiB
  __shared__ __align__(16) char Bs[2][BN * BK];  // 2 x 32 KiB

  // XCD-aware block swizzle (nwg=512, divisible by 8)
  const int nb = gridDim.x;
  const int swz = (blockIdx.x & 7) * (nb >> 3) + (blockIdx.x >> 3);
  const int bm = swz >> 4;        // M/BM = 32
  const int bn = swz & 15;        // N/BN = 16

  const int tid = threadIdx.x;
  const int wave = tid >> 6, lane = tid & 63;
  const int wr = wave >> 2, wc = wave & 3;   // 2 x 4 wave grid
  const int l15 = lane & 15, l7 = lane & 7, lk = lane >> 4;
  const int wr16l = wr * 16 + l15;
  const int wc16l = wc * 16 + l15;

  intx4 acc[8][4] = {};
  intx4 af[4][2];      // current A half (4 m-frags x 2 kk), overwritten/half
  intx4 bf[2][2][2];   // [slot: n01/n23][ni][kk]

  // Staging: one gload = 512 threads x 16B = 64 rows x 128B; 8 per tile
  // (J=0..3 per operand). LDS dest linear; global source chunk pre-swizzled
  // (involution): phys chunk (tid&7) of row (tid>>3) <- logical chunk
  // (tid&7) ^ ((tid>>3)&7).
  const int srow = tid >> 3;                       // 0..63
  const int sc16 = (tid & 7) ^ ((tid >> 3) & 7);
  const char* gA = A + (size_t)(bm * BM + srow) * K_TOT + sc16 * 16;
  const char* gB = B + (size_t)(bn * BN + srow) * K_TOT + sc16 * 16;

  // J = 64-row chunk (0..3); half h = chunks {2h, 2h+1}.
#define STAGE_A(P, J, KT)                                                 \
  gload_lds16(gA + (size_t)(J) * 64 * K_TOT + (size_t)(KT) * BK,          \
              As[P] + (J) * 8192 + wave * 1024)
#define STAGE_B(P, J, KT)                                                 \
  gload_lds16(gB + (size_t)(J) * 64 * K_TOT + (size_t)(KT) * BK,          \
              Bs[P] + (J) * 8192 + wave * 1024)

  // Swizzled fragment read: phys 16B-chunk = (lk + 4*kk) ^ (row&7);
  // all frag rows are (multiple of 16) + l15 -> row&7 == l7.
#define DS16(BASE, ROW, KK)                                               \
  *(const intx4*)((BASE) + (ROW) * BK + (((lk + 4 * (KK)) ^ l7) << 4))

#define LD_A03(P)                                                         \
  _Pragma("unroll") for (int mi = 0; mi < 4; ++mi) {                      \
    af[mi][0] = DS16(As[P], mi * 32 + wr16l, 0);                          \
    af[mi][1] = DS16(As[P], mi * 32 + wr16l, 1);                          \
  }
#define LD_A47(P)                                                         \
  _Pragma("unroll") for (int mi = 0; mi < 4; ++mi) {                      \
    af[mi][0] = DS16(As[P], (mi + 4) * 32 + wr16l, 0);                    \
    af[mi][1] = DS16(As[P], (mi + 4) * 32 + wr16l, 1);                    \
  }
#define LD_B01(P)                                                         \
  _Pragma("unroll") for (int ni = 0; ni < 2; ++ni) {                      \
    bf[0][ni][0] = DS16(Bs[P], ni * 64 + wc16l, 0);                       \
    bf[0][ni][1] = DS16(Bs[P], ni * 64 + wc16l, 1);                       \
  }
#define LD_B23(P)                                                         \
  _Pragma("unroll") for (int ni = 0; ni < 2; ++ni) {                      \
    bf[1][ni][0] = DS16(Bs[P], (ni + 2) * 64 + wc16l, 0);                 \
    bf[1][ni][1] = DS16(Bs[P], (ni + 2) * 64 + wc16l, 1);                 \
  }

  // Quadrant: 4 mi x 2 ni x 2 kk = 16 MFMA. MH = A half, NS = B slot.
#define MFMA_Q(MH, NS)                                                    \
  __builtin_amdgcn_s_setprio(1);                                          \
  _Pragma("unroll") for (int mi2 = 0; mi2 < 4; ++mi2)                     \
  _Pragma("unroll") for (int ni2 = 0; ni2 < 2; ++ni2)                     \
  _Pragma("unroll") for (int kk2 = 0; kk2 < 2; ++kk2)                     \
      acc[(MH) * 4 + mi2][(NS) * 2 + ni2] =                               \
          __builtin_amdgcn_mfma_i32_16x16x64_i8(                          \
              af[mi2][kk2], bf[NS][ni2][kk2],                             \
              acc[(MH) * 4 + mi2][(NS) * 2 + ni2], 0, 0, 0);              \
  __builtin_amdgcn_s_setprio(0)

  // ---- prologue: stage t0 (8 gloads), t1 (8); certify t0; bf01(t0) ----
  STAGE_B(0, 0, 0); STAGE_B(0, 1, 0); STAGE_A(0, 0, 0); STAGE_A(0, 1, 0);
  STAGE_B(0, 2, 0); STAGE_B(0, 3, 0); STAGE_A(0, 2, 0); STAGE_A(0, 3, 0);
  STAGE_B(1, 0, 1); STAGE_B(1, 1, 1); STAGE_A(1, 0, 1); STAGE_A(1, 1, 1);
  STAGE_B(1, 2, 1); STAGE_B(1, 3, 1); STAGE_A(1, 2, 1); STAGE_A(1, 3, 1);
  VMCNT(8);
  BAR();
  LD_B01(0);

  // ---- main loop: computes (t: buf0, t+1: buf1), stages (t+2, t+3).
  // Per phase: {ds_reads; stage 1 half-tile; [vmcnt(6) at ph4/ph8 BEFORE
  // the next-tile B read]; BAR; 16 MFMA; BAR}. vmcnt never 0 mid-loop.
  for (int t = 0; t + 3 < NT; t += 2) {
    // ph1: af03(buf0); stage B(t+2)h0
    LD_A03(0);
    STAGE_B(0, 0, t + 2); STAGE_B(0, 1, t + 2);
    BAR(); MFMA_Q(0, 0); BAR();
    // ph2: bf23(buf0); stage A(t+2)h0
    LD_B23(0);
    STAGE_A(0, 0, t + 2); STAGE_A(0, 1, t + 2);
    BAR(); MFMA_Q(0, 1); BAR();
    // ph3: af47(buf0); stage B(t+2)h1
    LD_A47(0);
    STAGE_B(0, 2, t + 2); STAGE_B(0, 3, t + 2);
    BAR(); MFMA_Q(1, 0); BAR();
    // ph4: vmcnt(6) certifies t+1 (3 staged halves in flight); bf01(buf1);
    //      stage A(t+2)h1
    VMCNT(6);
    LD_B01(1);
    STAGE_A(0, 2, t + 2); STAGE_A(0, 3, t + 2);
    BAR(); MFMA_Q(1, 1); BAR();
    // ph5: af03(buf1); stage B(t+3)h0
    LD_A03(1);
    STAGE_B(1, 0, t + 3); STAGE_B(1, 1, t + 3);
    BAR(); MFMA_Q(0, 0); BAR();
    // ph6: bf23(buf1); stage A(t+3)h0
    LD_B23(1);
    STAGE_A(1, 0, t + 3); STAGE_A(1, 1, t + 3);
    BAR(); MFMA_Q(0, 1); BAR();
    // ph7: af47(buf1); stage B(t+3)h1
    LD_A47(1);
    STAGE_B(1, 2, t + 3); STAGE_B(1, 3, t + 3);
    BAR(); MFMA_Q(1, 0); BAR();
    // ph8: vmcnt(6) certifies t+2; bf01(buf0); stage A(t+3)h1
    VMCNT(6);
    LD_B01(0);
    STAGE_A(1, 2, t + 3); STAGE_A(1, 3, t + 3);
    BAR(); MFMA_Q(1, 1); BAR();
  }

  // ---- tail: tiles NT-2 (buf0), NT-1 (buf1), no staging ----
  LD_A03(0); BAR(); MFMA_Q(0, 0); BAR();
  LD_B23(0); BAR(); MFMA_Q(0, 1); BAR();
  LD_A47(0); BAR(); MFMA_Q(1, 0); BAR();
  VMCNT(0);
  LD_B01(1); BAR(); MFMA_Q(1, 1); BAR();
  LD_A03(1); BAR(); MFMA_Q(0, 0); BAR();
  LD_B23(1); BAR(); MFMA_Q(0, 1); BAR();
  LD_A47(1); BAR(); MFMA_Q(1, 0); BAR();
  MFMA_Q(1, 1);

  // ---- epilogue: D mapping col=lane&15, row=(lane>>4)*4+e; dequant ----
  const size_t crow0 = (size_t)bm * BM + wr * 16 + (lk << 2);
  const int ccol0 = bn * BN + wc * 16 + l15;
  float sc4[4];
#pragma unroll
  for (int ni = 0; ni < 4; ++ni) sc4[ni] = scale[ccol0 + ni * 64];
#pragma unroll
  for (int mi = 0; mi < 8; ++mi) {
#pragma unroll
    for (int e = 0; e < 4; ++e) {
      const size_t r = crow0 + (size_t)mi * 32 + e;
      const float xr = XS[r];
#pragma unroll
      for (int ni = 0; ni < 4; ++ni)
        C[r * N_TOT + ccol0 + ni * 64] = (float)acc[mi][ni][e] * xr * sc4[ni];
    }
  }
}

// ---- fallback if workspace too small (insurance; slow but correct) ----
__global__ void naive_kernel(const float* __restrict__ x,
                             const int* __restrict__ w,
                             const float* __restrict__ s,
                             float* __restrict__ out) {
  int m = blockIdx.y;
  int n = blockIdx.x * 256 + threadIdx.x;
  const float* xr = x + (size_t)m * K_TOT;
  const int* wr = w + (size_t)n * K_TOT;
  float acc = 0.f;
  for (int k = 0; k < K_TOT; ++k) acc += xr[k] * (float)wr[k];
  out[(size_t)m * N_TOT + n] = acc * s[n];
}

extern "C" void kernel_launch(void* const* d_in, const int* in_sizes, int n_in,
                              void* d_out, int out_size, void* d_ws, size_t ws_size,
                              hipStream_t stream) {
  const float* x = (const float*)d_in[0];
  const int* w = (const int*)d_in[1];
  const float* scale = (const float*)d_in[2];
  float* out = (float*)d_out;

  const size_t x_elems = (size_t)M_TOT * K_TOT;   // i8 bytes
  const size_t w_elems = (size_t)N_TOT * K_TOT;   // i8 bytes
  const size_t need = x_elems + w_elems + M_TOT * sizeof(float);

  if (ws_size < need) {
    dim3 g(N_TOT / 256, M_TOT);
    naive_kernel<<<g, 256, 0, stream>>>(x, w, scale, out);
    return;
  }

  char* qx = (char*)d_ws;
  char* qw = qx + x_elems;
  float* xs = (float*)(qw + w_elems);

  const int prep_grid = M_TOT + (int)(w_elems / 16 / 256);  // 8192 + 4096
  prep_kernel<<<prep_grid, 256, 0, stream>>>(
      x, w, (int*)qx, xs, (int4*)qw);

  wq_gemm_kernel<<<(M_TOT / BM) * (N_TOT / BN), 512, 0, stream>>>(
      qx, qw, xs, scale, out);
}